// Round 1
// baseline (1448.527 us; speedup 1.0000x reference)
//
#include <hip/hip_runtime.h>

typedef unsigned char u8;
typedef unsigned int u32;
using f32x4 = __attribute__((ext_vector_type(4))) float;

#define E4M3_AMAX 216.0f
#define FP8_MAXV 240.0f

#define BM 128
#define BN 128
#define BK 64   // fp8 bytes along K per tile

#define GLD_LDS16(g, l) \
    __builtin_amdgcn_global_load_lds((const __attribute__((address_space(1))) void*)(g), \
                                     (__attribute__((address_space(3))) void*)(l), 16, 0, 0)

// ---------------- abs-max reduction (exact: uint compare on |f32| bits) ------
__global__ void maxabs_kernel(const float* __restrict__ x, long n4, u32* __restrict__ out) {
    long stride = (long)gridDim.x * blockDim.x;
    long i = (long)blockIdx.x * blockDim.x + threadIdx.x;
    u32 m = 0;
    const float4* x4 = (const float4*)x;
    for (long j = i; j < n4; j += stride) {
        float4 v = x4[j];
        u32 a = __float_as_uint(fabsf(v.x));
        u32 b = __float_as_uint(fabsf(v.y));
        u32 c = __float_as_uint(fabsf(v.z));
        u32 d = __float_as_uint(fabsf(v.w));
        m = a > m ? a : m;
        m = b > m ? b : m;
        m = c > m ? c : m;
        m = d > m ? d : m;
    }
    #pragma unroll
    for (int off = 32; off > 0; off >>= 1) {
        u32 o = (u32)__shfl_down((unsigned int)m, (unsigned int)off, 64);
        m = o > m ? o : m;
    }
    __shared__ u32 sm[8];
    int wave = threadIdx.x >> 6, lane = threadIdx.x & 63;
    if (lane == 0) sm[wave] = m;
    __syncthreads();
    if (threadIdx.x == 0) {
        u32 r = sm[0];
        int nw = blockDim.x >> 6;
        for (int w = 1; w < nw; ++w) r = sm[w] > r ? sm[w] : r;
        atomicMax(out, r);
    }
}

// ---------------- quantize f32 -> e4m3fn bytes (HW RNE cvt) ------------------
__global__ void quant_kernel(const float* __restrict__ x, u8* __restrict__ y, long n4,
                             const u32* __restrict__ maxbits, int idx) {
    float mx = __uint_as_float(maxbits[idx]);
    float scale = E4M3_AMAX / mx;
    long stride = (long)gridDim.x * blockDim.x;
    long i = (long)blockIdx.x * blockDim.x + threadIdx.x;
    const float4* x4 = (const float4*)x;
    int* y4 = (int*)y;
    for (long j = i; j < n4; j += stride) {
        float4 v = x4[j];
        float a = fminf(fmaxf(v.x * scale, -FP8_MAXV), FP8_MAXV);
        float b = fminf(fmaxf(v.y * scale, -FP8_MAXV), FP8_MAXV);
        float c = fminf(fmaxf(v.z * scale, -FP8_MAXV), FP8_MAXV);
        float d = fminf(fmaxf(v.w * scale, -FP8_MAXV), FP8_MAXV);
        int p = 0;
        p = __builtin_amdgcn_cvt_pk_fp8_f32(a, b, p, false);  // bytes 0,1
        p = __builtin_amdgcn_cvt_pk_fp8_f32(c, d, p, true);   // bytes 2,3
        y4[j] = p;
    }
}

// ---------------- fp8 GEMM: C[m,n] = sum_k A8[m,k]*W8[n,k], dequant + bias ---
// 128x128 block tile, 256 threads (4 waves), 64x64 per wave (4x4 of 16x16x32).
__global__ __launch_bounds__(256) void gemm_fp8_kernel(
    const u8* __restrict__ A,   // [M,K] fp8
    const u8* __restrict__ B,   // [N,K] fp8 (weight, K-contiguous = B^T form)
    const float* __restrict__ bias,
    const u32* __restrict__ scales,
    float* __restrict__ C, int M, int N, int K)
{
    __shared__ u8 As[BM * BK];   // row-major [128][64]
    __shared__ u8 Bs[BN * BK];

    const int tid = threadIdx.x;
    const int wave = tid >> 6;
    const int lane = tid & 63;
    const int fr = lane & 15;      // frag row (A) / col (B/D)
    const int quad = lane >> 4;    // 0..3

    const int bm = blockIdx.y * BM;
    const int bn = blockIdx.x * BN;
    const int wm = (wave >> 1) * 64;
    const int wn = (wave & 1) * 64;

    f32x4 acc[4][4] = {};

    // staging: each wave fills 2 chunks of 1024B per tile (chunk c = rows 16c..16c+15)
    // lane i of chunk writes LDS [chunk*1024 + i*16]; source row = 16c + i/4, colB = (i&3)*16
    const int srow = 16 * wave + (lane >> 2);
    const int scol = (lane & 3) * 16;
    const u8* gA = A + (size_t)(bm + srow) * K + scol;
    const u8* gB = B + (size_t)(bn + srow) * K + scol;
    u8* lA = As + wave * 1024;     // wave-uniform LDS base
    u8* lB = Bs + wave * 1024;

    for (int k0 = 0; k0 < K; k0 += BK) {
        GLD_LDS16(gA,              lA);
        GLD_LDS16(gA + (size_t)64 * K, lA + 4096);   // rows +64
        GLD_LDS16(gB,              lB);
        GLD_LDS16(gB + (size_t)64 * K, lB + 4096);
        gA += BK;
        gB += BK;
        __syncthreads();

        #pragma unroll
        for (int ks = 0; ks < 2; ++ks) {
            long a[4], b[4];
            #pragma unroll
            for (int i = 0; i < 4; ++i) {
                a[i] = *(const long*)(As + (wm + i * 16 + fr) * BK + ks * 32 + quad * 8);
                b[i] = *(const long*)(Bs + (wn + i * 16 + fr) * BK + ks * 32 + quad * 8);
            }
            #pragma unroll
            for (int i = 0; i < 4; ++i)
                #pragma unroll
                for (int j = 0; j < 4; ++j)
                    acc[i][j] = __builtin_amdgcn_mfma_f32_16x16x32_fp8_fp8(a[i], b[j], acc[i][j], 0, 0, 0);
        }
        __syncthreads();
    }

    // dequant epilogue: out = acc * (1/i_scale) * (1/w_scale) + bias
    const float mi = __uint_as_float(scales[0]);
    const float mw = __uint_as_float(scales[1]);
    const float i_scale = E4M3_AMAX / mi;
    const float w_scale = E4M3_AMAX / mw;
    const float deq = (1.0f / i_scale) * (1.0f / w_scale);

    #pragma unroll
    for (int i = 0; i < 4; ++i) {
        const int row0 = bm + wm + i * 16 + quad * 4;
        #pragma unroll
        for (int j = 0; j < 4; ++j) {
            const int col = bn + wn + j * 16 + fr;
            const float bv = bias[col];
            #pragma unroll
            for (int rg = 0; rg < 4; ++rg) {
                C[(size_t)(row0 + rg) * N + col] = acc[i][j][rg] * deq + bv;
            }
        }
    }
}

extern "C" void kernel_launch(void* const* d_in, const int* in_sizes, int n_in,
                              void* d_out, int out_size, void* d_ws, size_t ws_size,
                              hipStream_t stream) {
    const float* inp    = (const float*)d_in[0];
    const float* weight = (const float*)d_in[1];
    const float* bias   = (const float*)d_in[2];
    float* out = (float*)d_out;

    const int N = in_sizes[2];                        // 4096
    const int K = in_sizes[1] / N;                    // 4096
    const long icount = in_sizes[0];                  // 67108864
    const int M = (int)(icount / K);                  // 16384
    const long wcount = (long)N * K;

    u32* scales = (u32*)d_ws;
    u8* x8 = (u8*)d_ws + 256;
    u8* w8 = x8 + (size_t)M * K;

    // zero the amax accumulators (ws is poisoned 0xAA before each call)
    hipMemsetAsync(d_ws, 0, 16, stream);

    maxabs_kernel<<<2048, 256, 0, stream>>>(inp, icount / 4, scales + 0);
    maxabs_kernel<<<1024, 256, 0, stream>>>(weight, wcount / 4, scales + 1);

    quant_kernel<<<4096, 256, 0, stream>>>(inp, x8, icount / 4, scales, 0);
    quant_kernel<<<2048, 256, 0, stream>>>(weight, w8, wcount / 4, scales, 1);

    dim3 grid(N / BN, M / BM);
    gemm_fp8_kernel<<<grid, 256, 0, stream>>>(x8, w8, bias, scales, out, M, N, K);
}